// Round 6
// baseline (308.768 us; speedup 1.0000x reference)
//
#include <hip/hip_runtime.h>

typedef float f32x4 __attribute__((ext_vector_type(4)));
typedef short bf16x8 __attribute__((ext_vector_type(8)));
typedef short s16x4 __attribute__((ext_vector_type(4)));
typedef unsigned short u16;

#define B_ 8
#define C_ 512
#define N_ 4096
#define M_ 1024
#define P_ 128
// fixed-shift softmax: p = exp2(S*(1/(sqrt(128)*0.05))*log2e - 16*log2e)
#define A2C 2.5506631384888954f
#define B2C 23.083120654223414f

#define MFMA __builtin_amdgcn_mfma_f32_16x16x32_bf16

__device__ __forceinline__ u16 f2b(float f) {
  unsigned u = __float_as_uint(f);
  u += 0x7fffu + ((u >> 16) & 1u);   // RNE; inputs finite
  return (u16)(u >> 16);
}
__device__ __forceinline__ float b2f(u16 h) {
  return __uint_as_float(((unsigned)h) << 16);
}
__device__ __forceinline__ float waveRedSum(float v) {
#pragma unroll
  for (int off = 32; off > 0; off >>= 1) v += __shfl_xor(v, off);
  return v;
}
__device__ __forceinline__ void gload_lds16(const u16* g, u16* l) {
  __builtin_amdgcn_global_load_lds(
      (const __attribute__((address_space(1))) void*)g,
      (__attribute__((address_space(3))) void*)l, 16, 0, 0);
}

// ---------------------------------------------------------------------------
// Kernel 1: tile-transpose x -> xt bf16 [b][n][c]; 2x2 maxpool -> xdt bf16
// [b][m][c]; means of x, xd via atomics; mask-logit partials via atomics.
// grid: b(8) x ctile(8) x hpair(32) = 2048 blocks, 256 thr.
// ---------------------------------------------------------------------------
__global__ __launch_bounds__(256) void prep_tx(const float* __restrict__ x,
                                               const float* __restrict__ wm,
                                               u16* __restrict__ xt,
                                               u16* __restrict__ xdt,
                                               float* __restrict__ meanx,
                                               float* __restrict__ meanxd,
                                               float* __restrict__ logits) {
  const int bid = blockIdx.x;
  const int b = bid >> 8, ct = (bid >> 5) & 7, hp = bid & 31;
  const int t = threadIdx.x;
  const int lane = t & 63, wid = t >> 6;
  __shared__ float xs[64 * 133];
  __shared__ float part[4][64];
  const float* xb = x + ((size_t)(b * 512 + ct * 64) * 4096) + hp * 128;
#pragma unroll
  for (int it = 0; it < 32; ++it) {
    int c = it * 2 + (t >> 7);
    int n = t & 127;
    xs[c * 133 + n] = xb[(size_t)c * 4096 + n];
  }
  __syncthreads();
  // meanx partials
  {
    int c = t >> 2, qq = t & 3;
    float s = 0;
#pragma unroll
    for (int j = 0; j < 32; ++j) s += xs[c * 133 + qq * 32 + j];
    s += __shfl_xor(s, 1);
    s += __shfl_xor(s, 2);
    if (qq == 0) atomicAdd(&meanx[b * 512 + ct * 64 + c], s * (1.f / 4096.f));
  }
  // xt[b][n][c]
#pragma unroll
  for (int it = 0; it < 16; ++it) {
    int n = it * 8 + (t >> 5), cp2 = t & 31;
    float lo = xs[(2 * cp2) * 133 + n], hi = xs[(2 * cp2 + 1) * 133 + n];
    unsigned u = (unsigned)f2b(lo) | ((unsigned)f2b(hi) << 16);
    *(unsigned*)(xt + (((size_t)b * 4096) + hp * 128 + n) * 512 + ct * 64 + 2 * cp2) = u;
  }
  // pool -> xdt[b][m][c], meanxd partials, logit partials
  const int cp = t & 31;
  const float wm0 = wm[ct * 64 + 2 * cp], wm1 = wm[ct * 64 + 2 * cp + 1];
  float s0 = 0, s1 = 0;
#pragma unroll
  for (int it = 0; it < 4; ++it) {
    int wmi = it * 8 + (t >> 5);
    int c0 = 2 * cp;
    float a = fmaxf(fmaxf(xs[c0 * 133 + 2 * wmi], xs[c0 * 133 + 2 * wmi + 1]),
                    fmaxf(xs[c0 * 133 + 64 + 2 * wmi], xs[c0 * 133 + 64 + 2 * wmi + 1]));
    float d = fmaxf(fmaxf(xs[(c0 + 1) * 133 + 2 * wmi], xs[(c0 + 1) * 133 + 2 * wmi + 1]),
                    fmaxf(xs[(c0 + 1) * 133 + 64 + 2 * wmi], xs[(c0 + 1) * 133 + 64 + 2 * wmi + 1]));
    unsigned u = (unsigned)f2b(a) | ((unsigned)f2b(d) << 16);
    *(unsigned*)(xdt + (((size_t)b * 1024) + hp * 32 + wmi) * 512 + ct * 64 + c0) = u;
    s0 += a; s1 += d;
    // logit partial: sum over this 32-lane group's 64 channels
    float lg = wm0 * a + wm1 * d;
    lg += __shfl_xor(lg, 1);  lg += __shfl_xor(lg, 2);
    lg += __shfl_xor(lg, 4);  lg += __shfl_xor(lg, 8);
    lg += __shfl_xor(lg, 16);
    if (cp == 0) atomicAdd(&logits[b * 1024 + hp * 32 + wmi], lg);
  }
  s0 += __shfl_xor(s0, 32);
  s1 += __shfl_xor(s1, 32);
  if (lane < 32) { part[wid][2 * cp] = s0; part[wid][2 * cp + 1] = s1; }
  __syncthreads();
  if (t < 64)
    atomicAdd(&meanxd[b * 512 + ct * 64 + t],
              (part[0][t] + part[1][t] + part[2][t] + part[3][t]) * (1.f / 1024.f));
}

// ---------------------------------------------------------------------------
// Kernel 2: weight f2b casts (blocks 0..1535) | corr vectors (1536..1551)
// ---------------------------------------------------------------------------
__global__ __launch_bounds__(256) void wcvt(const float* __restrict__ wq,
                                            const float* __restrict__ wk,
                                            const float* __restrict__ wv,
                                            const float* __restrict__ meanx,
                                            const float* __restrict__ meanxd,
                                            u16* __restrict__ wq_b,
                                            u16* __restrict__ wk_b,
                                            u16* __restrict__ wv_b,
                                            float* __restrict__ corr_q,
                                            float* __restrict__ corr_k) {
  const int bid = blockIdx.x, t = threadIdx.x;
  if (bid < 1536) {
    int i = bid * 256 + t;
    if (i < 65536) wq_b[i] = f2b(wq[i]);
    else if (i < 131072) wk_b[i - 65536] = f2b(wk[i - 65536]);
    else wv_b[i - 131072] = f2b(wv[i - 131072]);
  } else {
    int blk = bid - 1536, b = blk & 7, sel = blk >> 3;
    const float* w = sel ? wk : wq;
    const float* mn = (sel ? meanxd : meanx) + b * 512;
    int p = t >> 1, h = t & 1;
    const float* wr = w + p * 512 + h * 256;
    const float* mr = mn + h * 256;
    float s = 0;
#pragma unroll 8
    for (int c = 0; c < 256; ++c) s += wr[c] * mr[c];
    s += __shfl_xor(s, 1);
    if (h == 0) (sel ? corr_k : corr_q)[b * 128 + p] = s;
  }
}

// ---------------------------------------------------------------------------
// Kernel 3: fused GEMMs. D[row][col] = A[row][:] . Bt[col][:]  (k=512)
// q: blocks [0,512); k: [512,640); v: [640,1152). BR=128, BC=64, 4 waves.
// ---------------------------------------------------------------------------
template <int BR, int BC, bool TRANS, bool CORR>
__device__ __forceinline__ void gemm_body(const u16* __restrict__ A,
                                          const u16* __restrict__ Bt,
                                          const float* __restrict__ corr,
                                          u16* __restrict__ outp,
                                          int Cout, int Ncols,
                                          int bx, int by, int b,
                                          u16 (*As)[72], u16 (*Bs)[72]) {
  constexpr int WR = BR / 2, WC = BC / 2, ITR = WR / 16, ITC = WC / 16;
  constexpr int AFR = BR * 8 / 256, BFR = BC * 8 / 256;
  const int col0 = bx * BC, row0 = by * BR;
  const int tid = threadIdx.x;
  const int lane = tid & 63, wid = tid >> 6;
  const int g = lane >> 4, c16 = lane & 15;
  const int wr = (wid >> 1) * WR, wc = (wid & 1) * WC;
  const u16* Bb = Bt + (size_t)b * Ncols * 512;
  f32x4 acc[ITR][ITC];
#pragma unroll
  for (int i = 0; i < ITR; ++i)
#pragma unroll
    for (int j = 0; j < ITC; ++j) acc[i][j] = (f32x4){0.f, 0.f, 0.f, 0.f};

  for (int k0 = 0; k0 < 512; k0 += 64) {
#pragma unroll
    for (int i = 0; i < AFR; ++i) {
      int f = tid + i * 256;
      int r = f >> 3, c8 = f & 7;
      *(bf16x8*)&As[r][c8 * 8] =
          *(const bf16x8*)(A + (size_t)(row0 + r) * 512 + k0 + c8 * 8);
    }
#pragma unroll
    for (int i = 0; i < BFR; ++i) {
      int f = tid + i * 256;
      int r = f >> 3, c8 = f & 7;
      *(bf16x8*)&Bs[r][c8 * 8] =
          *(const bf16x8*)(Bb + (size_t)(col0 + r) * 512 + k0 + c8 * 8);
    }
    __syncthreads();
#pragma unroll
    for (int kk = 0; kk < 2; ++kk) {
      bf16x8 bfr[ITC];
#pragma unroll
      for (int j = 0; j < ITC; ++j)
        bfr[j] = *(const bf16x8*)&Bs[wc + j * 16 + c16][kk * 32 + g * 8];
#pragma unroll
      for (int i = 0; i < ITR; ++i) {
        bf16x8 af = *(const bf16x8*)&As[wr + i * 16 + c16][kk * 32 + g * 8];
#pragma unroll
        for (int j = 0; j < ITC; ++j)
          acc[i][j] = MFMA(af, bfr[j], acc[i][j], 0, 0, 0);
      }
    }
    __syncthreads();
  }
  if (TRANS) {
#pragma unroll
    for (int i = 0; i < ITR; ++i)
#pragma unroll
      for (int j = 0; j < ITC; ++j) {
        int row = row0 + wr + i * 16 + g * 4;
        int col = col0 + wc + j * 16 + c16;
        s16x4 h;
#pragma unroll
        for (int r = 0; r < 4; ++r) {
          float val = acc[i][j][r];
          if (CORR) val -= corr[b * 128 + row + r];
          h[r] = (short)f2b(val);
        }
        *(s16x4*)(outp + ((size_t)b * Ncols + col) * Cout + row) = h;
      }
  } else {
#pragma unroll
    for (int i = 0; i < ITR; ++i)
#pragma unroll
      for (int j = 0; j < ITC; ++j) {
        int row = row0 + wr + i * 16 + g * 4;
        int col = col0 + wc + j * 16 + c16;
#pragma unroll
        for (int r = 0; r < 4; ++r)
          outp[((size_t)b * Cout + row + r) * Ncols + col] = f2b(acc[i][j][r]);
      }
  }
}

__global__ __launch_bounds__(256) void mega(const u16* __restrict__ wq_b,
                                            const u16* __restrict__ wk_b,
                                            const u16* __restrict__ wv_b,
                                            const u16* __restrict__ xt,
                                            const u16* __restrict__ xdt,
                                            const float* __restrict__ corr_q,
                                            const float* __restrict__ corr_k,
                                            u16* __restrict__ q_ws,
                                            u16* __restrict__ kt_ws,
                                            u16* __restrict__ v_ws) {
  __shared__ __align__(16) u16 As[128][72];
  __shared__ __align__(16) u16 Bs[64][72];
  const int bid = blockIdx.x;
  if (bid < 512) {
    gemm_body<128, 64, true, true>(wq_b, xt, corr_q, q_ws, 128, 4096,
                                   bid >> 3, 0, bid & 7, As, Bs);
  } else if (bid < 640) {
    int r = bid - 512;
    gemm_body<128, 64, true, true>(wk_b, xdt, corr_k, kt_ws, 128, 1024,
                                   r >> 3, 0, r & 7, As, Bs);
  } else {
    int r = bid - 640;
    gemm_body<128, 64, false, false>(wv_b, xdt, nullptr, v_ws, 512, 1024,
                                     (r >> 3) & 15, r >> 7, r & 7, As, Bs);
  }
}

// ---------------------------------------------------------------------------
// Kernel 4: softmax(logits) (redundant per block; bm shift-invariant -> drop)
// + gc[b][c] = v . p.  grid 128, 256 thr.
// ---------------------------------------------------------------------------
__global__ __launch_bounds__(256) void k_gc(const float* __restrict__ logits,
                                            const u16* __restrict__ v,
                                            float* __restrict__ gc) {
  const int b = blockIdx.x >> 4, cc = blockIdx.x & 15;
  const int tid = threadIdx.x;
  const int lane = tid & 63, wid = tid >> 6;
  __shared__ float pl[1024];
  __shared__ float r4[4];
  __shared__ float stot[2];
  float4 lv = *(const float4*)&logits[b * 1024 + tid * 4];
  float mx = fmaxf(fmaxf(lv.x, lv.y), fmaxf(lv.z, lv.w));
#pragma unroll
  for (int off = 32; off > 0; off >>= 1) mx = fmaxf(mx, __shfl_xor(mx, off));
  if (lane == 0) r4[wid] = mx;
  __syncthreads();
  if (tid == 0) stot[0] = fmaxf(fmaxf(r4[0], r4[1]), fmaxf(r4[2], r4[3]));
  __syncthreads();
  const float M = stot[0];
  float e0 = __expf(lv.x - M), e1 = __expf(lv.y - M);
  float e2 = __expf(lv.z - M), e3 = __expf(lv.w - M);
  pl[tid * 4 + 0] = e0; pl[tid * 4 + 1] = e1;
  pl[tid * 4 + 2] = e2; pl[tid * 4 + 3] = e3;
  float ps = waveRedSum((e0 + e1) + (e2 + e3));
  if (lane == 0) r4[wid] = ps;
  __syncthreads();
  if (tid == 0) stot[1] = 1.0f / (r4[0] + r4[1] + r4[2] + r4[3]);
  __syncthreads();
  const float inv = stot[1];
  const int c = cc * 32 + (tid >> 3), sub = tid & 7;
  const u16* vr = v + ((size_t)b * 512 + c) * 1024 + sub * 128;
  const float* plr = pl + sub * 128;
  float s = 0;
#pragma unroll
  for (int i = 0; i < 16; ++i) {
    bf16x8 h = *(const bf16x8*)(vr + i * 8);
#pragma unroll
    for (int j = 0; j < 8; ++j) s += b2f((u16)h[j]) * plr[i * 8 + j];
  }
  s += __shfl_xor(s, 1);
  s += __shfl_xor(s, 2);
  s += __shfl_xor(s, 4);
  if (sub == 0) gc[b * 512 + c] = s * inv;
}

// ---------------------------------------------------------------------------
// Kernel 5: flash attention, single-buffer LDS + counted-vmcnt, 2 blocks/CU.
// 512 thr = 8 waves; QB=64; grid 512: b=bid&7 (XCD), n0=(bid>>3)*64.
// LDS 74.75KB: Vl[512c][64m] swz (64KB), Pl[64n][64m] swz (8KB), l_s.
// step s: S(s) [K regs] -> issue K(s+1) -> P-write -> vmcnt(4) lgkm(0) -> B1
//         -> PV(s) (LDS) -> B2 -> issue V(s+1) gload_lds.
// Single buffers are safe: every ds_read is consumed by an MFMA before the
// barrier (compiler lgkmcnt), and gload writes are issued post-B2.
// ---------------------------------------------------------------------------
__global__ __launch_bounds__(512, 4) void attn(const u16* __restrict__ q,
                                               const u16* __restrict__ kt,
                                               const u16* __restrict__ v,
                                               const float* __restrict__ gc,
                                               const float* __restrict__ x,
                                               const float* __restrict__ gamma,
                                               float* __restrict__ out) {
  extern __shared__ __align__(16) char smem[];
  u16* Vl = (u16*)smem;                   // 512 x 64 halves (64 KB)
  u16* Pl = (u16*)(smem + 65536);         // 64 x 64 halves (8 KB)
  float* l_s = (float*)(smem + 73728);    // 256 floats
  const int bid = blockIdx.x;
  const int b = bid & 7;
  const int n0 = (bid >> 3) * 64;
  const int tid = threadIdx.x;
  const int lane = tid & 63, wid = tid >> 6;
  const int g = lane >> 4, c16 = lane & 15;
  const int mb = wid & 3, nh = wid >> 2;
  const int xsw = (c16 & 7) << 3;
  const int nA = nh * 32 + c16;
  const int po = (mb * 16 + g * 4) ^ xsw;

  bf16x8 qf[2][4];
  {
    const u16* qr = q + ((size_t)b * N_ + n0 + nh * 32 + c16) * P_ + g * 8;
#pragma unroll
    for (int t = 0; t < 2; ++t)
#pragma unroll
      for (int kf = 0; kf < 4; ++kf)
        qf[t][kf] = *(const bf16x8*)(qr + t * 16 * P_ + kf * 32);
  }
  const u16* ktr = kt + ((size_t)b * M_ + mb * 16 + c16) * P_ + g * 8;
  bf16x8 kb[4];
#pragma unroll
  for (int kf = 0; kf < 4; ++kf) kb[kf] = *(const bf16x8*)(ktr + kf * 32);
  const u16* kpre = ktr + 64 * P_;
  const u16* vst = v + ((size_t)b * C_ + wid * 64 + (lane >> 3)) * M_ +
                   ((lane & 7) ^ (lane >> 3)) * 8;
#pragma unroll
  for (int i = 0; i < 8; ++i)
    gload_lds16(vst + (size_t)i * 8 * M_, Vl + (wid * 8 + i) * 512);
  const u16* vpre = vst + 64;

  f32x4 acc[4][4];
#pragma unroll
  for (int i = 0; i < 4; ++i)
#pragma unroll
    for (int j = 0; j < 4; ++j) acc[i][j] = (f32x4){0.f, 0.f, 0.f, 0.f};
  float lp0 = 0.f, lp1 = 0.f;

  for (int s = 0; s < 16; ++s) {
    // ---- S(s) ----
    f32x4 sv0 = (f32x4){0.f, 0.f, 0.f, 0.f};
    f32x4 sv1 = (f32x4){0.f, 0.f, 0.f, 0.f};
#pragma unroll
    for (int kf = 0; kf < 4; ++kf) {
      sv0 = MFMA(kb[kf], qf[0][kf], sv0, 0, 0, 0);
      sv1 = MFMA(kb[kf], qf[1][kf], sv1, 0, 0, 0);
    }
    // issue K(s+1) (kb regs free: consumed above, in-order issue)
    if (s < 15) {
#pragma unroll
      for (int kf = 0; kf < 4; ++kf) kb[kf] = *(const bf16x8*)(kpre + kf * 32);
      kpre += 64 * P_;
    }
    // exp + l + pack + P write
    float p00 = exp2f(fmaf(sv0[0], A2C, -B2C));
    float p01 = exp2f(fmaf(sv0[1], A2C, -B2C));
    float p02 = exp2f(fmaf(sv0[2], A2C, -B2C));
    float p03 = exp2f(fmaf(sv0[3], A2C, -B2C));
    float p10 = exp2f(fmaf(sv1[0], A2C, -B2C));
    float p11 = exp2f(fmaf(sv1[1], A2C, -B2C));
    float p12 = exp2f(fmaf(sv1[2], A2C, -B2C));
    float p13 = exp2f(fmaf(sv1[3], A2C, -B2C));
    lp0 += (p00 + p01) + (p02 + p03);
    lp1 += (p10 + p11) + (p12 + p13);
    uint2 w0, w1;
    w0.x = (unsigned)f2b(p00) | ((unsigned)f2b(p01) << 16);
    w0.y = (unsigned)f2b(p02) | ((unsigned)f2b(p03) << 16);
    w1.x = (unsigned)f2b(p10) | ((unsigned)f2b(p11) << 16);
    w1.y = (unsigned)f2b(p12) | ((unsigned)f2b(p13) << 16);
    *(uint2*)&Pl[nA * 64 + po] = w0;
    *(uint2*)&Pl[(nA + 16) * 64 + po] = w1;
    if (s < 15) {
      asm volatile("s_waitcnt vmcnt(4) lgkmcnt(0)" ::: "memory");
    } else {
      asm volatile("s_waitcnt vmcnt(0) lgkmcnt(0)" ::: "memory");
    }
    __builtin_amdgcn_sched_barrier(0);
    __builtin_amdgcn_s_barrier();                       // B1: P+V visible
    __builtin_amdgcn_sched_barrier(0);
    // ---- PV(s) ----
#pragma unroll
    for (int kk = 0; kk < 2; ++kk) {
      bf16x8 pb[4];
#pragma unroll
      for (int nb = 0; nb < 4; ++nb)
        pb[nb] = *(const bf16x8*)&Pl[(nb * 16 + c16) * 64 + ((kk * 32 + g * 8) ^ xsw)];
#pragma unroll
      for (int cf = 0; cf < 4; ++cf) {
        bf16x8 va = *(const bf16x8*)&Vl[(wid * 64 + cf * 16 + c16) * 64 +
                                        ((kk * 32 + g * 8) ^ xsw)];
#pragma unroll
        for (int nb = 0; nb < 4; ++nb)
          acc[cf][nb] = MFMA(va, pb[nb], acc[cf][nb], 0, 0, 0);
      }
    }
    __builtin_amdgcn_sched_barrier(0);
    __builtin_amdgcn_s_barrier();                       // B2: Vl/Pl consumed
    __builtin_amdgcn_sched_barrier(0);
    // issue V(s+1)
    if (s < 15) {
#pragma unroll
      for (int i = 0; i < 8; ++i)
        gload_lds16(vpre + (size_t)i * 8 * M_, Vl + (wid * 8 + i) * 512);
      vpre += 64;
    }
  }

  // ---- l reduction ----
  lp0 += __shfl_xor(lp0, 16); lp0 += __shfl_xor(lp0, 32);
  lp1 += __shfl_xor(lp1, 16); lp1 += __shfl_xor(lp1, 32);
  if (lane < 16) {
    l_s[mb * 64 + nh * 32 + lane] = lp0;
    l_s[mb * 64 + nh * 32 + 16 + lane] = lp1;
  }
  __syncthreads();
  float linv[4];
#pragma unroll
  for (int nb = 0; nb < 4; ++nb) {
    int n = nb * 16 + c16;
    linv[nb] = 1.0f / (l_s[n] + l_s[64 + n] + l_s[128 + n] + l_s[192 + n]);
  }
  const float gam = gamma[0];
#pragma unroll
  for (int cf = 0; cf < 4; ++cf) {
    const int c = wid * 64 + cf * 16 + g * 4;
    float gcv[4];
#pragma unroll
    for (int r = 0; r < 4; ++r) gcv[r] = gc[b * C_ + c + r];
#pragma unroll
    for (int nb = 0; nb < 4; ++nb) {
      const size_t idx0 = ((size_t)b * C_ + c) * (size_t)N_ + n0 + nb * 16 + c16;
#pragma unroll
      for (int r = 0; r < 4; ++r) {
        const size_t idx = idx0 + (size_t)r * N_;
        out[idx] = gam * acc[cf][nb][r] * linv[nb] + gcv[r] + x[idx];
      }
    }
  }
}

// ---------------------------------------------------------------------------
extern "C" void kernel_launch(void* const* d_in, const int* in_sizes, int n_in,
                              void* d_out, int out_size, void* d_ws, size_t ws_size,
                              hipStream_t stream) {
  const float* x     = (const float*)d_in[0];
  const float* wq    = (const float*)d_in[1];
  const float* wk    = (const float*)d_in[3];
  const float* wv    = (const float*)d_in[5];
  const float* wm    = (const float*)d_in[6];
  const float* gamma = (const float*)d_in[8];
  float* out = (float*)d_out;
  char* ws = (char*)d_ws;

  u16*   xt     = (u16*)(ws + 0);          // 33,554,432
  u16*   xdt    = (u16*)(ws + 33554432);   //  8,388,608
  u16*   q_ws   = (u16*)(ws + 41943040);   //  8,388,608  [b][n][p]
  u16*   kt_ws  = (u16*)(ws + 50331648);   //  2,097,152  [b][m][p]
  u16*   v_ws   = (u16*)(ws + 52428800);   //  8,388,608  [b][c][m]
  u16*   wq_b   = (u16*)(ws + 60817408);   //    131,072
  u16*   wk_b   = (u16*)(ws + 60948480);   //    131,072
  u16*   wv_b   = (u16*)(ws + 61079552);   //    524,288
  float* meanx  = (float*)(ws + 61603840); //     16,384
  float* meanxd = (float*)(ws + 61620224); //     16,384
  float* logits = (float*)(ws + 61636608); //     32,768
  float* corr_q = (float*)(ws + 61669376); //      4,096
  float* corr_k = (float*)(ws + 61673472); //      4,096
  float* gc     = (float*)(ws + 61677568); //     16,384

  hipMemsetAsync(ws + 61603840, 0, 65536, stream);  // meanx+meanxd+logits
  prep_tx<<<dim3(2048), dim3(256), 0, stream>>>(x, wm, xt, xdt, meanx, meanxd,
                                                logits);
  wcvt<<<dim3(1552), dim3(256), 0, stream>>>(wq, wk, wv, meanx, meanxd,
                                             wq_b, wk_b, wv_b, corr_q, corr_k);
  mega<<<dim3(1152), dim3(256), 0, stream>>>(wq_b, wk_b, wv_b, xt, xdt,
                                             corr_q, corr_k, q_ws, kt_ws, v_ws);
  k_gc<<<dim3(128), dim3(256), 0, stream>>>(logits, v_ws, gc);

  hipFuncSetAttribute((const void*)attn,
                      hipFuncAttributeMaxDynamicSharedMemorySize, 74752);
  attn<<<dim3(512), dim3(512), 74752, stream>>>(q_ws, kt_ws, v_ws, gc, x,
                                                gamma, out);
}

// Round 7
// 251.029 us; speedup vs baseline: 1.2300x; 1.2300x over previous
//
#include <hip/hip_runtime.h>

typedef float f32x4 __attribute__((ext_vector_type(4)));
typedef short bf16x8 __attribute__((ext_vector_type(8)));
typedef short s16x4 __attribute__((ext_vector_type(4)));
typedef unsigned short u16;

#define B_ 8
#define C_ 512
#define N_ 4096
#define M_ 1024
#define P_ 128
// fixed-shift softmax: p = exp2(S*(1/(sqrt(128)*0.05))*log2e - 16*log2e)
#define A2C 2.5506631384888954f
#define B2C 23.083120654223414f

#define MFMA __builtin_amdgcn_mfma_f32_16x16x32_bf16

__device__ __forceinline__ u16 f2b(float f) {
  unsigned u = __float_as_uint(f);
  u += 0x7fffu + ((u >> 16) & 1u);   // RNE; inputs finite
  return (u16)(u >> 16);
}
__device__ __forceinline__ float b2f(u16 h) {
  return __uint_as_float(((unsigned)h) << 16);
}
__device__ __forceinline__ float waveRedSum(float v) {
#pragma unroll
  for (int off = 32; off > 0; off >>= 1) v += __shfl_xor(v, off);
  return v;
}
__device__ __forceinline__ void gload_lds16(const u16* g, u16* l) {
  __builtin_amdgcn_global_load_lds(
      (const __attribute__((address_space(1))) void*)g,
      (__attribute__((address_space(3))) void*)l, 16, 0, 0);
}

// ---------------------------------------------------------------------------
// Kernel 1: tile-transpose x -> xt bf16 [b][n][c]; 2x2 maxpool -> xdt bf16
// [b][m][c]; means of x, xd via atomics; mask-logit partials via atomics.
// grid: b(8) x ctile(8) x hpair(32) = 2048 blocks, 256 thr.
// ---------------------------------------------------------------------------
__global__ __launch_bounds__(256) void prep_tx(const float* __restrict__ x,
                                               const float* __restrict__ wm,
                                               u16* __restrict__ xt,
                                               u16* __restrict__ xdt,
                                               float* __restrict__ meanx,
                                               float* __restrict__ meanxd,
                                               float* __restrict__ logits) {
  const int bid = blockIdx.x;
  const int b = bid >> 8, ct = (bid >> 5) & 7, hp = bid & 31;
  const int t = threadIdx.x;
  const int lane = t & 63, wid = t >> 6;
  __shared__ float xs[64 * 133];
  __shared__ float part[4][64];
  const float* xb = x + ((size_t)(b * 512 + ct * 64) * 4096) + hp * 128;
#pragma unroll
  for (int it = 0; it < 32; ++it) {
    int c = it * 2 + (t >> 7);
    int n = t & 127;
    xs[c * 133 + n] = xb[(size_t)c * 4096 + n];
  }
  __syncthreads();
  // meanx partials
  {
    int c = t >> 2, qq = t & 3;
    float s = 0;
#pragma unroll
    for (int j = 0; j < 32; ++j) s += xs[c * 133 + qq * 32 + j];
    s += __shfl_xor(s, 1);
    s += __shfl_xor(s, 2);
    if (qq == 0) atomicAdd(&meanx[b * 512 + ct * 64 + c], s * (1.f / 4096.f));
  }
  // xt[b][n][c]
#pragma unroll
  for (int it = 0; it < 16; ++it) {
    int n = it * 8 + (t >> 5), cp2 = t & 31;
    float lo = xs[(2 * cp2) * 133 + n], hi = xs[(2 * cp2 + 1) * 133 + n];
    unsigned u = (unsigned)f2b(lo) | ((unsigned)f2b(hi) << 16);
    *(unsigned*)(xt + (((size_t)b * 4096) + hp * 128 + n) * 512 + ct * 64 + 2 * cp2) = u;
  }
  // pool -> xdt[b][m][c], meanxd partials, logit partials
  const int cp = t & 31;
  const float wm0 = wm[ct * 64 + 2 * cp], wm1 = wm[ct * 64 + 2 * cp + 1];
  float s0 = 0, s1 = 0;
#pragma unroll
  for (int it = 0; it < 4; ++it) {
    int wmi = it * 8 + (t >> 5);
    int c0 = 2 * cp;
    float a = fmaxf(fmaxf(xs[c0 * 133 + 2 * wmi], xs[c0 * 133 + 2 * wmi + 1]),
                    fmaxf(xs[c0 * 133 + 64 + 2 * wmi], xs[c0 * 133 + 64 + 2 * wmi + 1]));
    float d = fmaxf(fmaxf(xs[(c0 + 1) * 133 + 2 * wmi], xs[(c0 + 1) * 133 + 2 * wmi + 1]),
                    fmaxf(xs[(c0 + 1) * 133 + 64 + 2 * wmi], xs[(c0 + 1) * 133 + 64 + 2 * wmi + 1]));
    unsigned u = (unsigned)f2b(a) | ((unsigned)f2b(d) << 16);
    *(unsigned*)(xdt + (((size_t)b * 1024) + hp * 32 + wmi) * 512 + ct * 64 + c0) = u;
    s0 += a; s1 += d;
    // logit partial: sum over this 32-lane group's 64 channels
    float lg = wm0 * a + wm1 * d;
    lg += __shfl_xor(lg, 1);  lg += __shfl_xor(lg, 2);
    lg += __shfl_xor(lg, 4);  lg += __shfl_xor(lg, 8);
    lg += __shfl_xor(lg, 16);
    if (cp == 0) atomicAdd(&logits[b * 1024 + hp * 32 + wmi], lg);
  }
  s0 += __shfl_xor(s0, 32);
  s1 += __shfl_xor(s1, 32);
  if (lane < 32) { part[wid][2 * cp] = s0; part[wid][2 * cp + 1] = s1; }
  __syncthreads();
  if (t < 64)
    atomicAdd(&meanxd[b * 512 + ct * 64 + t],
              (part[0][t] + part[1][t] + part[2][t] + part[3][t]) * (1.f / 1024.f));
}

// ---------------------------------------------------------------------------
// Kernel 2: weight f2b casts (blocks 0..1535) | corr vectors (1536..1551)
// ---------------------------------------------------------------------------
__global__ __launch_bounds__(256) void wcvt(const float* __restrict__ wq,
                                            const float* __restrict__ wk,
                                            const float* __restrict__ wv,
                                            const float* __restrict__ meanx,
                                            const float* __restrict__ meanxd,
                                            u16* __restrict__ wq_b,
                                            u16* __restrict__ wk_b,
                                            u16* __restrict__ wv_b,
                                            float* __restrict__ corr_q,
                                            float* __restrict__ corr_k) {
  const int bid = blockIdx.x, t = threadIdx.x;
  if (bid < 1536) {
    int i = bid * 256 + t;
    if (i < 65536) wq_b[i] = f2b(wq[i]);
    else if (i < 131072) wk_b[i - 65536] = f2b(wk[i - 65536]);
    else wv_b[i - 131072] = f2b(wv[i - 131072]);
  } else {
    int blk = bid - 1536, b = blk & 7, sel = blk >> 3;
    const float* w = sel ? wk : wq;
    const float* mn = (sel ? meanxd : meanx) + b * 512;
    int p = t >> 1, h = t & 1;
    const float* wr = w + p * 512 + h * 256;
    const float* mr = mn + h * 256;
    float s = 0;
#pragma unroll 8
    for (int c = 0; c < 256; ++c) s += wr[c] * mr[c];
    s += __shfl_xor(s, 1);
    if (h == 0) (sel ? corr_k : corr_q)[b * 128 + p] = s;
  }
}

// ---------------------------------------------------------------------------
// Kernel 3: fused GEMMs. D[row][col] = A[row][:] . Bt[col][:]  (k=512)
// q: blocks [0,512); k: [512,640); v: [640,1152). BR=128, BC=64, 4 waves.
// ---------------------------------------------------------------------------
template <int BR, int BC, bool TRANS, bool CORR>
__device__ __forceinline__ void gemm_body(const u16* __restrict__ A,
                                          const u16* __restrict__ Bt,
                                          const float* __restrict__ corr,
                                          u16* __restrict__ outp,
                                          int Cout, int Ncols,
                                          int bx, int by, int b,
                                          u16 (*As)[72], u16 (*Bs)[72]) {
  constexpr int WR = BR / 2, WC = BC / 2, ITR = WR / 16, ITC = WC / 16;
  constexpr int AFR = BR * 8 / 256, BFR = BC * 8 / 256;
  const int col0 = bx * BC, row0 = by * BR;
  const int tid = threadIdx.x;
  const int lane = tid & 63, wid = tid >> 6;
  const int g = lane >> 4, c16 = lane & 15;
  const int wr = (wid >> 1) * WR, wc = (wid & 1) * WC;
  const u16* Bb = Bt + (size_t)b * Ncols * 512;
  f32x4 acc[ITR][ITC];
#pragma unroll
  for (int i = 0; i < ITR; ++i)
#pragma unroll
    for (int j = 0; j < ITC; ++j) acc[i][j] = (f32x4){0.f, 0.f, 0.f, 0.f};

  for (int k0 = 0; k0 < 512; k0 += 64) {
#pragma unroll
    for (int i = 0; i < AFR; ++i) {
      int f = tid + i * 256;
      int r = f >> 3, c8 = f & 7;
      *(bf16x8*)&As[r][c8 * 8] =
          *(const bf16x8*)(A + (size_t)(row0 + r) * 512 + k0 + c8 * 8);
    }
#pragma unroll
    for (int i = 0; i < BFR; ++i) {
      int f = tid + i * 256;
      int r = f >> 3, c8 = f & 7;
      *(bf16x8*)&Bs[r][c8 * 8] =
          *(const bf16x8*)(Bb + (size_t)(col0 + r) * 512 + k0 + c8 * 8);
    }
    __syncthreads();
#pragma unroll
    for (int kk = 0; kk < 2; ++kk) {
      bf16x8 bfr[ITC];
#pragma unroll
      for (int j = 0; j < ITC; ++j)
        bfr[j] = *(const bf16x8*)&Bs[wc + j * 16 + c16][kk * 32 + g * 8];
#pragma unroll
      for (int i = 0; i < ITR; ++i) {
        bf16x8 af = *(const bf16x8*)&As[wr + i * 16 + c16][kk * 32 + g * 8];
#pragma unroll
        for (int j = 0; j < ITC; ++j)
          acc[i][j] = MFMA(af, bfr[j], acc[i][j], 0, 0, 0);
      }
    }
    __syncthreads();
  }
  if (TRANS) {
#pragma unroll
    for (int i = 0; i < ITR; ++i)
#pragma unroll
      for (int j = 0; j < ITC; ++j) {
        int row = row0 + wr + i * 16 + g * 4;
        int col = col0 + wc + j * 16 + c16;
        s16x4 h;
#pragma unroll
        for (int r = 0; r < 4; ++r) {
          float val = acc[i][j][r];
          if (CORR) val -= corr[b * 128 + row + r];
          h[r] = (short)f2b(val);
        }
        *(s16x4*)(outp + ((size_t)b * Ncols + col) * Cout + row) = h;
      }
  } else {
#pragma unroll
    for (int i = 0; i < ITR; ++i)
#pragma unroll
      for (int j = 0; j < ITC; ++j) {
        int row = row0 + wr + i * 16 + g * 4;
        int col = col0 + wc + j * 16 + c16;
#pragma unroll
        for (int r = 0; r < 4; ++r)
          outp[((size_t)b * Cout + row + r) * Ncols + col] = f2b(acc[i][j][r]);
      }
  }
}

__global__ __launch_bounds__(256) void mega(const u16* __restrict__ wq_b,
                                            const u16* __restrict__ wk_b,
                                            const u16* __restrict__ wv_b,
                                            const u16* __restrict__ xt,
                                            const u16* __restrict__ xdt,
                                            const float* __restrict__ corr_q,
                                            const float* __restrict__ corr_k,
                                            u16* __restrict__ q_ws,
                                            u16* __restrict__ kt_ws,
                                            u16* __restrict__ v_ws) {
  __shared__ __align__(16) u16 As[128][72];
  __shared__ __align__(16) u16 Bs[64][72];
  const int bid = blockIdx.x;
  if (bid < 512) {
    gemm_body<128, 64, true, true>(wq_b, xt, corr_q, q_ws, 128, 4096,
                                   bid >> 3, 0, bid & 7, As, Bs);
  } else if (bid < 640) {
    int r = bid - 512;
    gemm_body<128, 64, true, true>(wk_b, xdt, corr_k, kt_ws, 128, 1024,
                                   r >> 3, 0, r & 7, As, Bs);
  } else {
    int r = bid - 640;
    gemm_body<128, 64, false, false>(wv_b, xdt, nullptr, v_ws, 512, 1024,
                                     (r >> 3) & 15, r >> 7, r & 7, As, Bs);
  }
}

// ---------------------------------------------------------------------------
// Kernel 4: softmax(logits) (redundant per block; bm shift-invariant -> drop)
// + gc[b][c] = v . p.  grid 128, 256 thr.
// ---------------------------------------------------------------------------
__global__ __launch_bounds__(256) void k_gc(const float* __restrict__ logits,
                                            const u16* __restrict__ v,
                                            float* __restrict__ gc) {
  const int b = blockIdx.x >> 4, cc = blockIdx.x & 15;
  const int tid = threadIdx.x;
  const int lane = tid & 63, wid = tid >> 6;
  __shared__ float pl[1024];
  __shared__ float r4[4];
  __shared__ float stot[2];
  float4 lv = *(const float4*)&logits[b * 1024 + tid * 4];
  float mx = fmaxf(fmaxf(lv.x, lv.y), fmaxf(lv.z, lv.w));
#pragma unroll
  for (int off = 32; off > 0; off >>= 1) mx = fmaxf(mx, __shfl_xor(mx, off));
  if (lane == 0) r4[wid] = mx;
  __syncthreads();
  if (tid == 0) stot[0] = fmaxf(fmaxf(r4[0], r4[1]), fmaxf(r4[2], r4[3]));
  __syncthreads();
  const float M = stot[0];
  float e0 = __expf(lv.x - M), e1 = __expf(lv.y - M);
  float e2 = __expf(lv.z - M), e3 = __expf(lv.w - M);
  pl[tid * 4 + 0] = e0; pl[tid * 4 + 1] = e1;
  pl[tid * 4 + 2] = e2; pl[tid * 4 + 3] = e3;
  float ps = waveRedSum((e0 + e1) + (e2 + e3));
  if (lane == 0) r4[wid] = ps;
  __syncthreads();
  if (tid == 0) stot[1] = 1.0f / (r4[0] + r4[1] + r4[2] + r4[3]);
  __syncthreads();
  const float inv = stot[1];
  const int c = cc * 32 + (tid >> 3), sub = tid & 7;
  const u16* vr = v + ((size_t)b * 512 + c) * 1024 + sub * 128;
  const float* plr = pl + sub * 128;
  float s = 0;
#pragma unroll
  for (int i = 0; i < 16; ++i) {
    bf16x8 h = *(const bf16x8*)(vr + i * 8);
#pragma unroll
    for (int j = 0; j < 8; ++j) s += b2f((u16)h[j]) * plr[i * 8 + j];
  }
  s += __shfl_xor(s, 1);
  s += __shfl_xor(s, 2);
  s += __shfl_xor(s, 4);
  if (sub == 0) gc[b * 512 + c] = s * inv;
}

// ---------------------------------------------------------------------------
// Kernel 5: flash attention, single-buffer LDS + counted-vmcnt.
// 512 thr = 8 waves; QB=64; grid 512: b=bid&7 (XCD), n0=(bid>>3)*64.
// LDS 74.75KB (2 blocks/CU); __launch_bounds__(512,2) -> ~120 VGPR, no spill
// (round-6 lesson: (512,4) forced a 64-reg cap and spilled acc to scratch).
// step s: S(s) [K regs] -> issue K(s+1) -> P-write -> vmcnt(4) lgkm(0) -> B1
//         -> PV(s) (LDS) -> B2 -> issue V(s+1) gload_lds.
// ---------------------------------------------------------------------------
__global__ __launch_bounds__(512, 2) void attn(const u16* __restrict__ q,
                                               const u16* __restrict__ kt,
                                               const u16* __restrict__ v,
                                               const float* __restrict__ gc,
                                               const float* __restrict__ x,
                                               const float* __restrict__ gamma,
                                               float* __restrict__ out) {
  extern __shared__ __align__(16) char smem[];
  u16* Vl = (u16*)smem;                   // 512 x 64 halves (64 KB)
  u16* Pl = (u16*)(smem + 65536);         // 64 x 64 halves (8 KB)
  float* l_s = (float*)(smem + 73728);    // 256 floats
  const int bid = blockIdx.x;
  const int b = bid & 7;
  const int n0 = (bid >> 3) * 64;
  const int tid = threadIdx.x;
  const int lane = tid & 63, wid = tid >> 6;
  const int g = lane >> 4, c16 = lane & 15;
  const int mb = wid & 3, nh = wid >> 2;
  const int xsw = (c16 & 7) << 3;
  const int nA = nh * 32 + c16;
  const int po = (mb * 16 + g * 4) ^ xsw;

  bf16x8 qf[2][4];
  {
    const u16* qr = q + ((size_t)b * N_ + n0 + nh * 32 + c16) * P_ + g * 8;
#pragma unroll
    for (int t = 0; t < 2; ++t)
#pragma unroll
      for (int kf = 0; kf < 4; ++kf)
        qf[t][kf] = *(const bf16x8*)(qr + t * 16 * P_ + kf * 32);
  }
  const u16* ktr = kt + ((size_t)b * M_ + mb * 16 + c16) * P_ + g * 8;
  bf16x8 kb[4];
#pragma unroll
  for (int kf = 0; kf < 4; ++kf) kb[kf] = *(const bf16x8*)(ktr + kf * 32);
  const u16* kpre = ktr + 64 * P_;
  const u16* vst = v + ((size_t)b * C_ + wid * 64 + (lane >> 3)) * M_ +
                   ((lane & 7) ^ (lane >> 3)) * 8;
#pragma unroll
  for (int i = 0; i < 8; ++i)
    gload_lds16(vst + (size_t)i * 8 * M_, Vl + (wid * 8 + i) * 512);
  const u16* vpre = vst + 64;

  f32x4 acc[4][4];
#pragma unroll
  for (int i = 0; i < 4; ++i)
#pragma unroll
    for (int j = 0; j < 4; ++j) acc[i][j] = (f32x4){0.f, 0.f, 0.f, 0.f};
  float lp0 = 0.f, lp1 = 0.f;

  for (int s = 0; s < 16; ++s) {
    // ---- S(s) ----
    f32x4 sv0 = (f32x4){0.f, 0.f, 0.f, 0.f};
    f32x4 sv1 = (f32x4){0.f, 0.f, 0.f, 0.f};
#pragma unroll
    for (int kf = 0; kf < 4; ++kf) {
      sv0 = MFMA(kb[kf], qf[0][kf], sv0, 0, 0, 0);
      sv1 = MFMA(kb[kf], qf[1][kf], sv1, 0, 0, 0);
    }
    // issue K(s+1) (kb regs free: consumed above, in-order issue)
    if (s < 15) {
#pragma unroll
      for (int kf = 0; kf < 4; ++kf) kb[kf] = *(const bf16x8*)(kpre + kf * 32);
      kpre += 64 * P_;
    }
    // exp + l + pack + P write
    float p00 = exp2f(fmaf(sv0[0], A2C, -B2C));
    float p01 = exp2f(fmaf(sv0[1], A2C, -B2C));
    float p02 = exp2f(fmaf(sv0[2], A2C, -B2C));
    float p03 = exp2f(fmaf(sv0[3], A2C, -B2C));
    float p10 = exp2f(fmaf(sv1[0], A2C, -B2C));
    float p11 = exp2f(fmaf(sv1[1], A2C, -B2C));
    float p12 = exp2f(fmaf(sv1[2], A2C, -B2C));
    float p13 = exp2f(fmaf(sv1[3], A2C, -B2C));
    lp0 += (p00 + p01) + (p02 + p03);
    lp1 += (p10 + p11) + (p12 + p13);
    uint2 w0, w1;
    w0.x = (unsigned)f2b(p00) | ((unsigned)f2b(p01) << 16);
    w0.y = (unsigned)f2b(p02) | ((unsigned)f2b(p03) << 16);
    w1.x = (unsigned)f2b(p10) | ((unsigned)f2b(p11) << 16);
    w1.y = (unsigned)f2b(p12) | ((unsigned)f2b(p13) << 16);
    *(uint2*)&Pl[nA * 64 + po] = w0;
    *(uint2*)&Pl[(nA + 16) * 64 + po] = w1;
    if (s < 15) {
      asm volatile("s_waitcnt vmcnt(4) lgkmcnt(0)" ::: "memory");
    } else {
      asm volatile("s_waitcnt vmcnt(0) lgkmcnt(0)" ::: "memory");
    }
    __builtin_amdgcn_sched_barrier(0);
    __builtin_amdgcn_s_barrier();                       // B1: P+V visible
    __builtin_amdgcn_sched_barrier(0);
    // ---- PV(s) ----
#pragma unroll
    for (int kk = 0; kk < 2; ++kk) {
      bf16x8 pb[4];
#pragma unroll
      for (int nb = 0; nb < 4; ++nb)
        pb[nb] = *(const bf16x8*)&Pl[(nb * 16 + c16) * 64 + ((kk * 32 + g * 8) ^ xsw)];
#pragma unroll
      for (int cf = 0; cf < 4; ++cf) {
        bf16x8 va = *(const bf16x8*)&Vl[(wid * 64 + cf * 16 + c16) * 64 +
                                        ((kk * 32 + g * 8) ^ xsw)];
#pragma unroll
        for (int nb = 0; nb < 4; ++nb)
          acc[cf][nb] = MFMA(va, pb[nb], acc[cf][nb], 0, 0, 0);
      }
    }
    __builtin_amdgcn_sched_barrier(0);
    __builtin_amdgcn_s_barrier();                       // B2: Vl/Pl consumed
    __builtin_amdgcn_sched_barrier(0);
    // issue V(s+1)
    if (s < 15) {
#pragma unroll
      for (int i = 0; i < 8; ++i)
        gload_lds16(vpre + (size_t)i * 8 * M_, Vl + (wid * 8 + i) * 512);
      vpre += 64;
    }
  }

  // ---- l reduction ----
  lp0 += __shfl_xor(lp0, 16); lp0 += __shfl_xor(lp0, 32);
  lp1 += __shfl_xor(lp1, 16); lp1 += __shfl_xor(lp1, 32);
  if (lane < 16) {
    l_s[mb * 64 + nh * 32 + lane] = lp0;
    l_s[mb * 64 + nh * 32 + 16 + lane] = lp1;
  }
  __syncthreads();
  float linv[4];
#pragma unroll
  for (int nb = 0; nb < 4; ++nb) {
    int n = nb * 16 + c16;
    linv[nb] = 1.0f / (l_s[n] + l_s[64 + n] + l_s[128 + n] + l_s[192 + n]);
  }
  const float gam = gamma[0];
#pragma unroll
  for (int cf = 0; cf < 4; ++cf) {
    const int c = wid * 64 + cf * 16 + g * 4;
    float gcv[4];
#pragma unroll
    for (int r = 0; r < 4; ++r) gcv[r] = gc[b * C_ + c + r];
#pragma unroll
    for (int nb = 0; nb < 4; ++nb) {
      const size_t idx0 = ((size_t)b * C_ + c) * (size_t)N_ + n0 + nb * 16 + c16;
#pragma unroll
      for (int r = 0; r < 4; ++r) {
        const size_t idx = idx0 + (size_t)r * N_;
        out[idx] = gam * acc[cf][nb][r] * linv[nb] + gcv[r] + x[idx];
      }
    }
  }
}

// ---------------------------------------------------------------------------
extern "C" void kernel_launch(void* const* d_in, const int* in_sizes, int n_in,
                              void* d_out, int out_size, void* d_ws, size_t ws_size,
                              hipStream_t stream) {
  const float* x     = (const float*)d_in[0];
  const float* wq    = (const float*)d_in[1];
  const float* wk    = (const float*)d_in[3];
  const float* wv    = (const float*)d_in[5];
  const float* wm    = (const float*)d_in[6];
  const float* gamma = (const float*)d_in[8];
  float* out = (float*)d_out;
  char* ws = (char*)d_ws;

  u16*   xt     = (u16*)(ws + 0);          // 33,554,432
  u16*   xdt    = (u16*)(ws + 33554432);   //  8,388,608
  u16*   q_ws   = (u16*)(ws + 41943040);   //  8,388,608  [b][n][p]
  u16*   kt_ws  = (u16*)(ws + 50331648);   //  2,097,152  [b][m][p]
  u16*   v_ws   = (u16*)(ws + 52428800);   //  8,388,608  [b][c][m]
  u16*   wq_b   = (u16*)(ws + 60817408);   //    131,072
  u16*   wk_b   = (u16*)(ws + 60948480);   //    131,072
  u16*   wv_b   = (u16*)(ws + 61079552);   //    524,288
  float* meanx  = (float*)(ws + 61603840); //     16,384
  float* meanxd = (float*)(ws + 61620224); //     16,384
  float* logits = (float*)(ws + 61636608); //     32,768
  float* corr_q = (float*)(ws + 61669376); //      4,096
  float* corr_k = (float*)(ws + 61673472); //      4,096
  float* gc     = (float*)(ws + 61677568); //     16,384

  hipMemsetAsync(ws + 61603840, 0, 65536, stream);  // meanx+meanxd+logits
  prep_tx<<<dim3(2048), dim3(256), 0, stream>>>(x, wm, xt, xdt, meanx, meanxd,
                                                logits);
  wcvt<<<dim3(1552), dim3(256), 0, stream>>>(wq, wk, wv, meanx, meanxd,
                                             wq_b, wk_b, wv_b, corr_q, corr_k);
  mega<<<dim3(1152), dim3(256), 0, stream>>>(wq_b, wk_b, wv_b, xt, xdt,
                                             corr_q, corr_k, q_ws, kt_ws, v_ws);
  k_gc<<<dim3(128), dim3(256), 0, stream>>>(logits, v_ws, gc);

  hipFuncSetAttribute((const void*)attn,
                      hipFuncAttributeMaxDynamicSharedMemorySize, 74752);
  attn<<<dim3(512), dim3(512), 74752, stream>>>(q_ws, kt_ws, v_ws, gc, x,
                                                gamma, out);
}